// Round 6
// baseline (371.295 us; speedup 1.0000x reference)
//
#include <hip/hip_runtime.h>

#define D 512
#define H1 1024
#define NNODES 50000
#define NEDGES 400000
#define MPAD 50176   // 196 * 256
#define NEG_SLOPE 0.2f
#define SCAN_BLOCKS 196   // 196*256 = 50176 >= 50000

typedef __attribute__((ext_vector_type(8))) short bf16x8;
typedef __attribute__((ext_vector_type(8))) unsigned short u16x8;
typedef __attribute__((ext_vector_type(4))) float f32x4;

// packed operand layout for GEMM staging:
// addr(r, k) = ((r>>7)*(K>>3) + (k>>3))*1024 + (r&127)*8 + (k&7)
// -> a 64-lane global_load_lds segment (64 rows x one 8-k chunk) is one
//    contiguous 1KB burst; LDS image is linear and conflict-free (2-way).

__device__ __forceinline__ unsigned short f2bf(float f) {
  unsigned int u = __float_as_uint(f);
  unsigned int r = u + 0x7FFFu + ((u >> 16) & 1u);
  return (unsigned short)(r >> 16);
}
__device__ __forceinline__ float bf2f(unsigned short h) {
  return __uint_as_float((unsigned int)h << 16);
}

__device__ __forceinline__ void gl_lds16(const void* g, void* l) {
  __builtin_amdgcn_global_load_lds(
      (const __attribute__((address_space(1))) void*)g,
      (__attribute__((address_space(3))) void*)l, 16, 0, 0);
}

// key[j] = sum_i cond[i] * Wk[i][j],  Wk is (256, 2D) row-major
__global__ void key_kernel(const float* __restrict__ cond, const float* __restrict__ Wk,
                           float* __restrict__ key) {
  int j = blockIdx.x * blockDim.x + threadIdx.x;
  if (j >= 2 * D) return;
  float s = 0.f;
#pragma unroll 8
  for (int i = 0; i < 256; ++i) s += cond[i] * Wk[i * (2 * D) + j];
  key[j] = s;
}

// one wave per node: nki/nkj dots + emit xb = bf16(x) row-major.
__global__ void nodedot_kernel(const float* __restrict__ x, const float* __restrict__ key,
                               float* __restrict__ nki, float* __restrict__ nkj,
                               unsigned short* __restrict__ xb) {
  int wid = (blockIdx.x * blockDim.x + threadIdx.x) >> 6;
  int lane = threadIdx.x & 63;
  if (wid >= NNODES) return;
  const float4* xr = (const float4*)(x + (size_t)wid * D);
  float4 p0 = xr[2 * lane], p1 = xr[2 * lane + 1];
  const float4* kia = (const float4*)key;
  const float4* kja = (const float4*)(key + D);
  float4 q0 = kia[2 * lane], q1 = kia[2 * lane + 1];
  float4 r0 = kja[2 * lane], r1 = kja[2 * lane + 1];
  float a = p0.x * q0.x + p0.y * q0.y + p0.z * q0.z + p0.w * q0.w +
            p1.x * q1.x + p1.y * q1.y + p1.z * q1.z + p1.w * q1.w;
  float b = p0.x * r0.x + p0.y * r0.y + p0.z * r0.z + p0.w * r0.w +
            p1.x * r1.x + p1.y * r1.y + p1.z * r1.z + p1.w * r1.w;
  u16x8 h;
  h[0] = f2bf(p0.x); h[1] = f2bf(p0.y); h[2] = f2bf(p0.z); h[3] = f2bf(p0.w);
  h[4] = f2bf(p1.x); h[5] = f2bf(p1.y); h[6] = f2bf(p1.z); h[7] = f2bf(p1.w);
  *(u16x8*)(xb + (size_t)wid * D + 8 * lane) = h;
#pragma unroll
  for (int off = 32; off > 0; off >>= 1) {
    a += __shfl_xor(a, off);
    b += __shfl_xor(b, off);
  }
  if (lane == 0) { nki[wid] = a; nkj[wid] = b; }
}

// W1 (D,2D) -> W1t packed (R=H1, K=D) ; W2 (2D,D) -> W2t packed (R=D, K=H1)
__global__ void convw_kernel(const float* __restrict__ W1, const float* __restrict__ W2,
                             unsigned short* __restrict__ W1t, unsigned short* __restrict__ W2t) {
  int idx = blockIdx.x * blockDim.x + threadIdx.x;
  if (idx >= D * H1) return;
  {
    int k = idx / H1, n = idx % H1;
    size_t a = (((size_t)(n >> 7) * (D >> 3) + (k >> 3)) << 10) + ((n & 127) << 3) + (k & 7);
    W1t[a] = f2bf(W1[idx]);
  }
  {
    int k = idx / D, n = idx % D;
    size_t a = (((size_t)(n >> 7) * (H1 >> 3) + (k >> 3)) << 10) + ((n & 127) << 3) + (k & 7);
    W2t[a] = f2bf(W2[idx]);
  }
}

// ---- CSR build ----
__global__ void zero_deg_kernel(int* __restrict__ deg) {
  int i = blockIdx.x * blockDim.x + threadIdx.x;
  if (i < NNODES) deg[i] = 0;
}

__global__ void hist_kernel(const int* __restrict__ row, int* __restrict__ deg) {
  int e = blockIdx.x * blockDim.x + threadIdx.x;
  if (e < NEDGES) atomicAdd(&deg[row[e]], 1);
}

__global__ void scan1_kernel(const int* __restrict__ deg, int* __restrict__ rowptr,
                             int* __restrict__ blktot) {
  __shared__ int s[256];
  int tid = threadIdx.x;
  int i = blockIdx.x * 256 + tid;
  int v = (i < NNODES) ? deg[i] : 0;
  s[tid] = v;
  __syncthreads();
#pragma unroll
  for (int off = 1; off < 256; off <<= 1) {
    int t = (tid >= off) ? s[tid - off] : 0;
    __syncthreads();
    s[tid] += t;
    __syncthreads();
  }
  if (i < NNODES) rowptr[i] = s[tid] - v;
  if (tid == 255) blktot[blockIdx.x] = s[255];
}

__global__ void scan2_kernel(int* __restrict__ blktot, int* __restrict__ blkoff) {
  __shared__ int s[256];
  int tid = threadIdx.x;
  int v = (tid < SCAN_BLOCKS) ? blktot[tid] : 0;
  s[tid] = v;
  __syncthreads();
#pragma unroll
  for (int off = 1; off < 256; off <<= 1) {
    int t = (tid >= off) ? s[tid - off] : 0;
    __syncthreads();
    s[tid] += t;
    __syncthreads();
  }
  if (tid < SCAN_BLOCKS) blkoff[tid] = s[tid] - v;
}

__global__ void scan3_kernel(int* __restrict__ rowptr, const int* __restrict__ blkoff,
                             int* __restrict__ cursor) {
  int i = blockIdx.x * blockDim.x + threadIdx.x;
  if (i < NNODES) {
    int v = rowptr[i] + blkoff[blockIdx.x];
    rowptr[i] = v;
    cursor[i] = v;
  }
  if (i == 0) rowptr[NNODES] = NEDGES;
}

// per edge: alpha = sigmoid(leaky(nki[col]+nkj[row])); place (col,alpha) into CSR slot
__global__ void fill_kernel(const int* __restrict__ row, const int* __restrict__ col,
                            const float* __restrict__ nki, const float* __restrict__ nkj,
                            int* __restrict__ cursor, int* __restrict__ scol,
                            float* __restrict__ salpha) {
  int e = blockIdx.x * blockDim.x + threadIdx.x;
  if (e >= NEDGES) return;
  int r = row[e], c = col[e];
  float a = nki[c] + nkj[r];
  a = (a >= 0.f) ? a : NEG_SLOPE * a;
  float al = 1.f / (1.f + expf(-a));
  int pos = atomicAdd(&cursor[r], 1);
  scol[pos] = c;
  salpha[pos] = al;
}

// one wave per node: Pb[n] = bf16(xb[n] + sum_e alpha_e * xb[scol[e]]), packed out.
__global__ __launch_bounds__(256) void agg_kernel(
    const unsigned short* __restrict__ xb, const int* __restrict__ rowptr,
    const int* __restrict__ scol, const float* __restrict__ salpha,
    unsigned short* __restrict__ Pb) {
  int n = (blockIdx.x * blockDim.x + threadIdx.x) >> 6;
  int lane = threadIdx.x & 63;
  if (n >= NNODES) return;
  int beg = rowptr[n], end = rowptr[n + 1];
  u16x8 self = *(const u16x8*)(xb + (size_t)n * D + 8 * lane);
  float sa[8], sb[8];
#pragma unroll
  for (int q = 0; q < 8; ++q) { sa[q] = bf2f(self[q]); sb[q] = 0.f; }
  int e = beg;
  for (; e + 1 < end; e += 2) {
    int c0 = scol[e], c1 = scol[e + 1];
    float al0 = salpha[e], al1 = salpha[e + 1];
    u16x8 w0 = *(const u16x8*)(xb + (size_t)c0 * D + 8 * lane);
    u16x8 w1 = *(const u16x8*)(xb + (size_t)c1 * D + 8 * lane);
#pragma unroll
    for (int q = 0; q < 8; ++q) {
      sa[q] += al0 * bf2f(w0[q]);
      sb[q] += al1 * bf2f(w1[q]);
    }
  }
  if (e < end) {
    int c0 = scol[e];
    float al0 = salpha[e];
    u16x8 w0 = *(const u16x8*)(xb + (size_t)c0 * D + 8 * lane);
#pragma unroll
    for (int q = 0; q < 8; ++q) sa[q] += al0 * bf2f(w0[q]);
  }
  u16x8 h;
#pragma unroll
  for (int q = 0; q < 8; ++q) h[q] = f2bf(sa[q] + sb[q]);
  *(u16x8*)(Pb + (((size_t)(n >> 7) * (D >> 3) + lane) << 10) + ((n & 127) << 3)) = h;
}

// C = act(A @ Bt^T + bias). A, Bt PACKED. 256x256 tile, BK=64, 8 waves (2M x 4N,
// each wave 128x64 out). Double-buffered LDS (128KB), counted-vmcnt pipeline:
// loads for tiles t+1/t+2 stay in flight across raw s_barriers (T3/T4), setprio
// around MFMA clusters (T5). K compile-time.
template <int K, bool RELU_OUT_BF16>
__global__ __launch_bounds__(512, 2) void gemm_kernel(
    const unsigned short* __restrict__ Ag, const unsigned short* __restrict__ Bt,
    const float* __restrict__ bias, void* __restrict__ Cptr, int M_valid, int N) {
  constexpr int KC = K >> 3;  // # of 8-elem k-chunks per row-block
  constexpr int NT = K >> 6;  // # of 64-wide k-tiles
  __shared__ unsigned short As[2 * 2 * 8 * 128 * 8];  // [buf][rb][kc][row][8], 64KB
  __shared__ unsigned short Bs[2 * 2 * 8 * 128 * 8];

  // bijective XCD-chunked swizzle (grid multiple of 8 here)
  const int G = gridDim.x * gridDim.y;
  const int orig = blockIdx.y * gridDim.x + blockIdx.x;
  const int wg = (orig & 7) * (G >> 3) + (orig >> 3);
  const int bx = wg % gridDim.x;
  const int by = wg / gridDim.x;

  const int tid = threadIdx.x;
  const int lane = tid & 63;
  const int wave = tid >> 6;
  const int wr = wave >> 2;  // 0..1 : M half (128 rows)
  const int wc = wave & 3;   // 0..3 : N quarter (64 cols)
  const int fr = lane & 15;
  const int kq = lane >> 4;  // 0..3

  f32x4 acc[8][4];
#pragma unroll
  for (int i = 0; i < 8; ++i)
#pragma unroll
    for (int j = 0; j < 4; ++j)
#pragma unroll
      for (int r = 0; r < 4; ++r) acc[i][j][r] = 0.f;

  // stage k-tile t into buffer b: 8 gl_lds16 per thread (4 A + 4 B)
  auto stage = [&](int b, int t) {
#pragma unroll
    for (int ss = 0; ss < 4; ++ss) {
      const int s = wave * 4 + ss;  // 0..31 : rb*16 + kc*2 + half
      const int rb = s >> 4, kc = (s >> 1) & 7, half = s & 1;
      const int kca = t * 8 + kc;
      gl_lds16(Ag + (((size_t)(by * 2 + rb) * KC + kca) << 10) + (half * 64 + lane) * 8,
               &As[((b * 2 + rb) * 8 + kc) * 1024 + half * 512]);
      gl_lds16(Bt + (((size_t)(bx * 2 + rb) * KC + kca) << 10) + (half * 64 + lane) * 8,
               &Bs[((b * 2 + rb) * 8 + kc) * 1024 + half * 512]);
    }
  };

  const int rbB = wc >> 1;
  const int rowB = (wc & 1) * 64;

  stage(0, 0);
  stage(1, 1);

  for (int t = 0; t < NT - 1; ++t) {
    const int cur = t & 1;
    asm volatile("s_waitcnt vmcnt(8)" ::: "memory");  // tile t resident; t+1 in flight
    __builtin_amdgcn_s_barrier();
    __builtin_amdgcn_sched_barrier(0);

    // ---- half 0: kc = kq ----
    {
      const int kc = kq;
      bf16x8 af[8], bfv[4];
#pragma unroll
      for (int i = 0; i < 8; ++i)
        af[i] = *(const bf16x8*)&As[((cur * 2 + wr) * 8 + kc) * 1024 + (i * 16 + fr) * 8];
#pragma unroll
      for (int j = 0; j < 4; ++j)
        bfv[j] = *(const bf16x8*)&Bs[((cur * 2 + rbB) * 8 + kc) * 1024 + (rowB + j * 16 + fr) * 8];
      __builtin_amdgcn_s_setprio(1);
#pragma unroll
      for (int i = 0; i < 8; ++i)
#pragma unroll
        for (int j = 0; j < 4; ++j)
          acc[i][j] = __builtin_amdgcn_mfma_f32_16x16x32_bf16(af[i], bfv[j], acc[i][j], 0, 0, 0);
      __builtin_amdgcn_s_setprio(0);
    }

    // ---- half 1 reads: kc = 4 + kq ----
    bf16x8 af1[8], bf1[4];
    {
      const int kc = 4 + kq;
#pragma unroll
      for (int i = 0; i < 8; ++i)
        af1[i] = *(const bf16x8*)&As[((cur * 2 + wr) * 8 + kc) * 1024 + (i * 16 + fr) * 8];
#pragma unroll
      for (int j = 0; j < 4; ++j)
        bf1[j] = *(const bf16x8*)&Bs[((cur * 2 + rbB) * 8 + kc) * 1024 + (rowB + j * 16 + fr) * 8];
    }
    asm volatile("s_waitcnt lgkmcnt(0)" ::: "memory");  // this wave done reading buf[cur]
    __builtin_amdgcn_sched_barrier(0);
    __builtin_amdgcn_s_barrier();                        // all waves done -> safe to overwrite
    if (t + 2 < NT) stage(cur, t + 2);                   // prefetch under h1 MFMA
    __builtin_amdgcn_sched_barrier(0);
    __builtin_amdgcn_s_setprio(1);
#pragma unroll
    for (int i = 0; i < 8; ++i)
#pragma unroll
      for (int j = 0; j < 4; ++j)
        acc[i][j] = __builtin_amdgcn_mfma_f32_16x16x32_bf16(af1[i], bf1[j], acc[i][j], 0, 0, 0);
    __builtin_amdgcn_s_setprio(0);
  }

  // ---- final tile ----
  {
    const int cur = (NT - 1) & 1;
    asm volatile("s_waitcnt vmcnt(0)" ::: "memory");
    __builtin_amdgcn_s_barrier();
    __builtin_amdgcn_sched_barrier(0);
#pragma unroll
    for (int h = 0; h < 2; ++h) {
      const int kc = h * 4 + kq;
      bf16x8 af[8], bfv[4];
#pragma unroll
      for (int i = 0; i < 8; ++i)
        af[i] = *(const bf16x8*)&As[((cur * 2 + wr) * 8 + kc) * 1024 + (i * 16 + fr) * 8];
#pragma unroll
      for (int j = 0; j < 4; ++j)
        bfv[j] = *(const bf16x8*)&Bs[((cur * 2 + rbB) * 8 + kc) * 1024 + (rowB + j * 16 + fr) * 8];
      __builtin_amdgcn_s_setprio(1);
#pragma unroll
      for (int i = 0; i < 8; ++i)
#pragma unroll
        for (int j = 0; j < 4; ++j)
          acc[i][j] = __builtin_amdgcn_mfma_f32_16x16x32_bf16(af[i], bfv[j], acc[i][j], 0, 0, 0);
      __builtin_amdgcn_s_setprio(0);
    }
  }

  // epilogue: C/D layout col = lane&15, row = (lane>>4)*4 + reg
  const int rg = kq * 4;
#pragma unroll
  for (int j = 0; j < 4; ++j) {
    const int gn = bx * 256 + wc * 64 + j * 16 + fr;
    const float bv = bias[gn];
#pragma unroll
    for (int i = 0; i < 8; ++i) {
#pragma unroll
      for (int r = 0; r < 4; ++r) {
        const int lrow = wr * 128 + i * 16 + rg + r;
        const int gm = by * 256 + lrow;
        float v = acc[i][j][r] + bv;
        if constexpr (RELU_OUT_BF16) {
          v = fmaxf(v, 0.f);
          size_t a = (((size_t)(gm >> 7) * (N >> 3) + (gn >> 3)) << 10) + ((gm & 127) << 3) + (gn & 7);
          ((unsigned short*)Cptr)[a] = f2bf(v);
        } else {
          if (gm < M_valid) ((float*)Cptr)[(size_t)gm * N + gn] = v;
        }
      }
    }
  }
}

extern "C" void kernel_launch(void* const* d_in, const int* in_sizes, int n_in,
                              void* d_out, int out_size, void* d_ws, size_t ws_size,
                              hipStream_t stream) {
  const float* x    = (const float*)d_in[0];
  const int*   ei   = (const int*)d_in[1];
  const float* cond = (const float*)d_in[2];
  const float* Wk   = (const float*)d_in[3];
  const float* W1   = (const float*)d_in[4];
  const float* b1   = (const float*)d_in[5];
  const float* W2   = (const float*)d_in[6];
  const float* b2   = (const float*)d_in[7];
  float* out = (float*)d_out;

  char* ws = (char*)d_ws;
  size_t off = 0;
  auto alloc = [&](size_t b) { size_t p = off; off += (b + 255) & ~(size_t)255; return p; };
  float* key = (float*)(ws + alloc(2 * D * sizeof(float)));
  float* nki = (float*)(ws + alloc(NNODES * sizeof(float)));
  float* nkj = (float*)(ws + alloc(NNODES * sizeof(float)));
  int* deg    = (int*)(ws + alloc(NNODES * sizeof(int)));
  int* rowptr = (int*)(ws + alloc((NNODES + 1) * sizeof(int)));
  int* cursor = (int*)(ws + alloc(NNODES * sizeof(int)));
  int* blktot = (int*)(ws + alloc(SCAN_BLOCKS * sizeof(int)));
  int* blkoff = (int*)(ws + alloc(SCAN_BLOCKS * sizeof(int)));
  int* scol      = (int*)(ws + alloc(NEDGES * sizeof(int)));
  float* salpha  = (float*)(ws + alloc(NEDGES * sizeof(float)));
  unsigned short* xb  = (unsigned short*)(ws + alloc((size_t)NNODES * D * 2));  // bf16 x, row-major
  unsigned short* W1t = (unsigned short*)(ws + alloc((size_t)H1 * D * 2));      // packed (R=H1,K=D)
  unsigned short* W2t = (unsigned short*)(ws + alloc((size_t)D * H1 * 2));      // packed (R=D,K=H1)
  unsigned short* Pb  = (unsigned short*)(ws + alloc((size_t)MPAD * D * 2));    // packed (R=MPAD,K=D)
  unsigned short* Hb  = (unsigned short*)(ws + alloc((size_t)MPAD * H1 * 2));   // packed (R=MPAD,K=H1)

  const int* row = ei;
  const int* col = ei + NEDGES;

  key_kernel<<<dim3((2 * D + 255) / 256), dim3(256), 0, stream>>>(cond, Wk, key);
  nodedot_kernel<<<dim3(NNODES * 64 / 256), dim3(256), 0, stream>>>(x, key, nki, nkj, xb);
  convw_kernel<<<dim3(D * H1 / 256), dim3(256), 0, stream>>>(W1, W2, W1t, W2t);

  // CSR build
  zero_deg_kernel<<<dim3(SCAN_BLOCKS), dim3(256), 0, stream>>>(deg);
  hist_kernel<<<dim3((NEDGES + 255) / 256), dim3(256), 0, stream>>>(row, deg);
  scan1_kernel<<<dim3(SCAN_BLOCKS), dim3(256), 0, stream>>>(deg, rowptr, blktot);
  scan2_kernel<<<dim3(1), dim3(256), 0, stream>>>(blktot, blkoff);
  scan3_kernel<<<dim3(SCAN_BLOCKS), dim3(256), 0, stream>>>(rowptr, blkoff, cursor);
  fill_kernel<<<dim3((NEDGES + 255) / 256), dim3(256), 0, stream>>>(row, col, nki, nkj,
                                                                    cursor, scol, salpha);
  // aggregate: Pb = bf16(xb + segment_sum(alpha * xb[col])), packed
  agg_kernel<<<dim3(NNODES * 64 / 256 + 1), dim3(256), 0, stream>>>(xb, rowptr, scol, salpha, Pb);

  // GEMM1: Hb = relu(Pb @ W1 + b1)   [M=50176, K=512, N=1024]  grid 4x196 (784 %8==0)
  gemm_kernel<512, true><<<dim3(H1 / 256, MPAD / 256), dim3(512), 0, stream>>>(
      Pb, W1t, b1, Hb, NNODES, H1);
  // GEMM2: out = Hb @ W2 + b2        [M=50176, K=1024, N=512]  grid 2x196 (392 %8==0)
  gemm_kernel<1024, false><<<dim3(D / 256, MPAD / 256), dim3(512), 0, stream>>>(
      Hb, W2t, b2, out, NNODES, D);
}